// Round 7
// baseline (564.677 us; speedup 1.0000x reference)
//
#include <hip/hip_runtime.h>

// ConvEmbedding: out[b,t,c] = bias[c] + sum_k W[c, x[b,t+k-4], k]
// B=8, T=4096, H=512, V=32000, K=9.
//
// R7: direct gather, zero intermediate. Overlap-add per source token:
// W[c, v, 0..9) is 36 CONTIGUOUS bytes -> one 36B read per (c, s), taps
// accumulate into a 9-deep register ring (shift-register convolution).
// Wave = (batch, 64-channel group, 64-t stripe); lane = channel; per step one
// coalesced 256B store of out[t, c0..c0+63]. Zero-pad via uniform halo skips.
// HBM ~= 547 MB (W, compulsory) + halo + 67 MB (out) ~= 680 MB total.

#define Hc 512
#define Vc 32000
#define Kc 9
#define Tc 4096
#define Bc 8
#define Mc (Vc * Kc)  // 288000

struct F3 { float x, y, z; };

// One step of the sliding-window conv. PH = j%9 (compile-time), taps
// k=KMIN..KMAX, ring slot (PH-k+9)%9; completed slot (PH+1)%9 stored.
template <int PH, int KMIN, int KMAX, bool DO_STORE>
__device__ __forceinline__ void step(const int* ids, int j,
                                     const float* __restrict__ Wc,
                                     float (&acc)[9], float bc, float*& outp,
                                     bool taps_ok) {
  if (taps_ok) {
    const int v = ids[j];
    const F3* p = (const F3*)(Wc + (size_t)v * Kc);
    const F3 r0 = p[0], r1 = p[1], r2 = p[2];
    const float w[9] = {r0.x, r0.y, r0.z, r1.x, r1.y,
                        r1.z, r2.x, r2.y, r2.z};
#pragma unroll
    for (int k = KMIN; k <= KMAX; ++k) acc[(PH - k + 9) % 9] += w[k];
  }
  if (DO_STORE) {
    *outp = acc[(PH + 1) % 9] + bc;
    acc[(PH + 1) % 9] = 0.0f;
    outp += Hc;
  }
}

// grid = 1024: b(8) x stripe(64) x half(2); block = 256 (4 waves = 4 c-groups)
__global__ __launch_bounds__(256) void conv_direct_kernel(
    const int* __restrict__ x, const float* __restrict__ W,
    const float* __restrict__ bias, float* __restrict__ out) {
  __shared__ int ids[72];
  const int blk = blockIdx.x;
  const int half = blk & 1;
  const int stripe = (blk >> 1) & 63;
  const int b = blk >> 7;
  const int t0 = stripe * 64;
  const int tid = threadIdx.x;
  if (tid < 72) {
    int s = t0 - 4 + tid;
    s = s < 0 ? 0 : (s > Tc - 1 ? Tc - 1 : s);
    ids[tid] = x[b * Tc + s];
  }
  __syncthreads();
  const int lane = tid & 63;
  const int c = (half * 4 + (tid >> 6)) * 64 + lane;
  const float* Wc = W + (size_t)c * Mc;
  const float bc = bias[c];
  float* outp = out + ((size_t)(b * Tc + t0) << 9) + c;
  float acc[9] = {0, 0, 0, 0, 0, 0, 0, 0, 0};

  const bool lo = (t0 != 0);       // head-halo s>=0 fails only for stripe 0
  const bool hi = (t0 != Tc - 64); // tail-halo s<T fails only for last stripe

  // g=0: j=ph, s=t0-4+ph, taps k=0..ph (t>=t0), store only at ph=8 (t0 done)
  step<0, 0, 0, false>(ids, 0, Wc, acc, bc, outp, lo);
  step<1, 0, 1, false>(ids, 1, Wc, acc, bc, outp, lo);
  step<2, 0, 2, false>(ids, 2, Wc, acc, bc, outp, lo);
  step<3, 0, 3, false>(ids, 3, Wc, acc, bc, outp, lo);
  step<4, 0, 4, false>(ids, 4, Wc, acc, bc, outp, true);
  step<5, 0, 5, false>(ids, 5, Wc, acc, bc, outp, true);
  step<6, 0, 6, false>(ids, 6, Wc, acc, bc, outp, true);
  step<7, 0, 7, false>(ids, 7, Wc, acc, bc, outp, true);
  step<8, 0, 8, true>(ids, 8, Wc, acc, bc, outp, true);

  // g=1..6: j=9g+ph, s always in-range, all taps, store every step
#pragma unroll 1
  for (int g = 1; g < 7; ++g) {
    const int j0 = 9 * g;
    step<0, 0, 8, true>(ids, j0 + 0, Wc, acc, bc, outp, true);
    step<1, 0, 8, true>(ids, j0 + 1, Wc, acc, bc, outp, true);
    step<2, 0, 8, true>(ids, j0 + 2, Wc, acc, bc, outp, true);
    step<3, 0, 8, true>(ids, j0 + 3, Wc, acc, bc, outp, true);
    step<4, 0, 8, true>(ids, j0 + 4, Wc, acc, bc, outp, true);
    step<5, 0, 8, true>(ids, j0 + 5, Wc, acc, bc, outp, true);
    step<6, 0, 8, true>(ids, j0 + 6, Wc, acc, bc, outp, true);
    step<7, 0, 8, true>(ids, j0 + 7, Wc, acc, bc, outp, true);
    step<8, 0, 8, true>(ids, j0 + 8, Wc, acc, bc, outp, true);
  }

  // g=7: j=63+ph, s=t0+59+ph, taps k=ph..8 (t < t0+64), store every step;
  // s >= T only possible for the last stripe at ph>=5.
  step<0, 0, 8, true>(ids, 63, Wc, acc, bc, outp, true);
  step<1, 1, 8, true>(ids, 64, Wc, acc, bc, outp, true);
  step<2, 2, 8, true>(ids, 65, Wc, acc, bc, outp, true);
  step<3, 3, 8, true>(ids, 66, Wc, acc, bc, outp, true);
  step<4, 4, 8, true>(ids, 67, Wc, acc, bc, outp, true);
  step<5, 5, 8, true>(ids, 68, Wc, acc, bc, outp, hi);
  step<6, 6, 8, true>(ids, 69, Wc, acc, bc, outp, hi);
  step<7, 7, 8, true>(ids, 70, Wc, acc, bc, outp, hi);
  step<8, 8, 8, true>(ids, 71, Wc, acc, bc, outp, hi);
}

extern "C" void kernel_launch(void* const* d_in, const int* in_sizes, int n_in,
                              void* d_out, int out_size, void* d_ws, size_t ws_size,
                              hipStream_t stream) {
  const int* x = (const int*)d_in[0];
  const float* W = (const float*)d_in[1];
  const float* bias = (const float*)d_in[2];
  float* out = (float*)d_out;
  conv_direct_kernel<<<Bc * 64 * 2, 256, 0, stream>>>(x, W, bias, out);
}

// Round 8
// 301.073 us; speedup vs baseline: 1.8755x; 1.8755x over previous
//
#include <hip/hip_runtime.h>

// ConvEmbedding: out[b,t,c] = bias[c] + sum_k W[c, x[b,t+k-4], k]
// B=8, T=4096, H=512, V=32000, K=9.
//
// R8: 8 SERIAL 64-channel chunks, single compact Wt buffer.
// Phase working set = 74 MB W stream + 23.4 MB Wt + 8.4 MB out << 256 MB MALL
// (R6's 128-c chunks were 262 MB -> thrashed by a hair). Gather i reads Wt
// from Infinity Cache; transpose i+1 re-dirties the same buffer in place.
// nt hints keep the W stream / out stores from evicting Wt. Vectorized:
// float2 transpose loads (512 B/inst), uint2 gather loads (256 B/inst).

#define Hc 512
#define Vc 32000
#define Kc 9
#define Tc 4096
#define Bc 8
#define Mc (Vc * Kc)              // 288000
#define CHUNK_C 64
#define NCHUNK 8
#define ROW_U (Kc * CHUNK_C / 2)  // 288 uints = 1152 B per slot row per chunk
#define WT_ROWS (Vc + 1)          // all-distinct worst case + zero row
#define MT 128                    // m per transpose tile
#define T_TILE 64

typedef float f4v __attribute__((ext_vector_type(4)));

__device__ __forceinline__ unsigned int f2bf(float f) {
  unsigned int u = __float_as_uint(f);
  u += 0x7FFFu + ((u >> 16) & 1u);  // round-to-nearest-even
  return u >> 16;
}

// Assign compact slots (1..) to touched vocab ids; slot[] pre-set -1. Slot 0
// is the zero row (sequence-boundary padding).
__global__ __launch_bounds__(256) void mark_kernel(
    const int* __restrict__ x, int* __restrict__ slot, int* __restrict__ counter) {
  const int i = blockIdx.x * 256 + threadIdx.x;  // B*T = 32768
  const int v = x[i];
  if (atomicCAS(&slot[v], -1, -2147483647) == -1) {
    slot[v] = 1 + atomicAdd(counter, 1);
  }
}

// Transpose one 64-c chunk of W into compact Wt. grid = 2250 (128-m tiles).
__global__ __launch_bounds__(256) void transpose_chunk_kernel(
    const float* __restrict__ W, const int* __restrict__ slot,
    unsigned int* __restrict__ wbuf, int chunk) {
  __shared__ float tile[MT][CHUNK_C + 1];
  const int m0 = blockIdx.x * MT;
  const int cbase = chunk * CHUNK_C;
  const int tid = threadIdx.x;
  const int tx = tid & 63;
  const int ty = tid >> 6;  // 0..3
  // load 64 c-rows x 128 m, float2 per lane: 512 B per wave-instr
#pragma unroll
  for (int i = 0; i < 16; ++i) {
    const int cr = i * 4 + ty;
    const double* p =
        (const double*)(W + (size_t)(cbase + cr) * Mc + m0) + tx;
    const double d = __builtin_nontemporal_load(p);
    const float2 f = *(const float2*)&d;
    tile[2 * tx][cr] = f.x;
    tile[2 * tx + 1][cr] = f.y;
  }
  __syncthreads();
  // write: 16 passes x (8 m-rows x 32 uints); 128 B contiguous per m-row
  const int u = tid & 31;
  const int rl = tid >> 5;  // 0..7
#pragma unroll
  for (int p = 0; p < 16; ++p) {
    const int mr = p * 8 + rl;
    const int m = m0 + mr;
    const int v = m / Kc;
    const int k = m - v * Kc;
    const int s = slot[v];
    if (s >= 0) {
      const unsigned int val =
          f2bf(tile[mr][2 * u]) | (f2bf(tile[mr][2 * u + 1]) << 16);
      wbuf[(size_t)s * ROW_U + k * 32 + u] = val;
    }
  }
}

// Gather one 64-c chunk. grid = 512 (8 b x 64 t-stripes), block 256.
__global__ __launch_bounds__(256) void gather_chunk_kernel(
    const int* __restrict__ x, const int* __restrict__ slot,
    const unsigned int* __restrict__ rbuf, const float* __restrict__ bias,
    float* __restrict__ out, int chunk) {
  __shared__ int ids[T_TILE + Kc - 1];  // 72 compact slot ids
  const int gb = blockIdx.x;
  const int b = gb >> 6;
  const int t0 = (gb & 63) * T_TILE;
  const int tid = threadIdx.x;
  if (tid < T_TILE + Kc - 1) {
    const int s = t0 + tid - (Kc / 2);
    ids[tid] = (s >= 0 && s < Tc) ? slot[x[b * Tc + s]] : 0;
  }
  __syncthreads();
  const int cq = tid & 15;  // c-quad index (4 channels)
  const int r = tid >> 4;   // 0..15, each handles 4 consecutive t
  const int c0 = chunk * CHUNK_C;
  const f4v b4 = *(const f4v*)(bias + c0 + 4 * cq);
  const uint2* rb2 = (const uint2*)rbuf;  // Wt row = 144 uint2
#pragma unroll
  for (int i = 0; i < 4; ++i) {
    const int tt = r * 4 + i;
    f4v acc = b4;
#pragma unroll
    for (int k = 0; k < Kc; ++k) {
      const int id = ids[tt + k];
      const uint2 wv = rb2[(size_t)id * (ROW_U / 2) + k * 16 + cq];
      acc.x += __uint_as_float(wv.x << 16);
      acc.y += __uint_as_float(wv.x & 0xFFFF0000u);
      acc.z += __uint_as_float(wv.y << 16);
      acc.w += __uint_as_float(wv.y & 0xFFFF0000u);
    }
    __builtin_nontemporal_store(
        acc, (f4v*)(out + ((size_t)(b * Tc + t0 + tt) << 9) + c0 + 4 * cq));
  }
}

// Fallback (ws too small): direct, slow but correct.
__global__ __launch_bounds__(256) void conv_fallback_kernel(
    const int* __restrict__ x, const float* __restrict__ W,
    const float* __restrict__ bias, float* __restrict__ out) {
  const size_t idx = (size_t)blockIdx.x * 256 + threadIdx.x;
  const int c = (int)(idx & (Hc - 1));
  const size_t bt = idx >> 9;
  const int t = (int)(bt & (Tc - 1));
  const int b = (int)(bt >> 12);
  float acc = bias[c];
#pragma unroll
  for (int k = 0; k < Kc; ++k) {
    const int s = t + k - (Kc / 2);
    if (s >= 0 && s < Tc) {
      const int id = x[b * Tc + s];
      acc += W[(size_t)c * Mc + (size_t)id * Kc + k];
    }
  }
  out[idx] = acc;
}

extern "C" void kernel_launch(void* const* d_in, const int* in_sizes, int n_in,
                              void* d_out, int out_size, void* d_ws, size_t ws_size,
                              hipStream_t stream) {
  const int* x = (const int*)d_in[0];
  const float* W = (const float*)d_in[1];
  const float* bias = (const float*)d_in[2];
  float* out = (float*)d_out;

  // ws layout: one Wt chunk buffer (worst-case rows), slot[V], counter
  const size_t buf_bytes = (size_t)WT_ROWS * ROW_U * 4;  // 36,865,152 B
  const size_t slot_off = buf_bytes;
  const size_t cnt_off = slot_off + (size_t)Vc * 4;
  const size_t need = cnt_off + 4;

  if (ws_size >= need) {
    unsigned int* buf = (unsigned int*)d_ws;
    int* slot = (int*)((char*)d_ws + slot_off);
    int* counter = (int*)((char*)d_ws + cnt_off);
    hipMemsetAsync(slot, 0xFF, (size_t)Vc * 4, stream);
    hipMemsetAsync(counter, 0, 4, stream);
    hipMemsetAsync(buf, 0, ROW_U * 4, stream);  // zero row (slot 0)
    mark_kernel<<<(Bc * Tc) / 256, 256, 0, stream>>>(x, slot, counter);
    for (int chunk = 0; chunk < NCHUNK; ++chunk) {
      transpose_chunk_kernel<<<Mc / MT, 256, 0, stream>>>(W, slot, buf, chunk);
      gather_chunk_kernel<<<Bc * (Tc / T_TILE), 256, 0, stream>>>(
          x, slot, buf, bias, out, chunk);
    }
  } else {
    const size_t n = (size_t)Bc * Tc * Hc;
    conv_fallback_kernel<<<(int)(n / 256), 256, 0, stream>>>(x, W, bias, out);
  }
}

// Round 9
// 240.892 us; speedup vs baseline: 2.3441x; 1.2498x over previous
//
#include <hip/hip_runtime.h>

// ConvEmbedding: out[b,t,c] = bias[c] + sum_k W[c, x[b,t+k-4], k]
// B=8, T=4096, H=512, V=32000, K=9.
//
// R9: minimal 2-phase, efficiency-tuned.
//  - transpose tiles 32m x 256c: 128B-aligned m-span -> every global load
//    inst = 8 whole cache lines, no cross-block line sharing
//  - Wt layout [s][k][c] (compact s): per-m 512B c-segments, a block's 32 m
//    form 2-4.6KB contiguous runs per slot row -> good write combining
//  - gather: uint2 loads (4 ch/thread), nt float4 stores
//  - 5 launches: memset(slot), memset(counter), mark(+zero-row), transpose,
//    gather. Model: writes always cost HBM; floor ~= 590+188+188+67 MB.

#define Hc 512
#define Vc 32000
#define Kc 9
#define Tc 4096
#define Bc 8
#define Mc (Vc * Kc)       // 288000
#define WT_ROWS (Vc + 1)   // worst case all distinct + zero row
#define ROW_U (Kc * Hc / 2)  // 2304 uints = 9216 B per slot row
#define T_TILE 32

typedef float f4v __attribute__((ext_vector_type(4)));

__device__ __forceinline__ unsigned int f2bf(float f) {
  unsigned int u = __float_as_uint(f);
  u += 0x7FFFu + ((u >> 16) & 1u);  // round-to-nearest-even
  return u >> 16;
}

// Assign compact slots (1..) to touched vocab ids; slot[] pre-set -1.
// Blocks 0..8 also zero Wt row 0 (the boundary zero row).
__global__ __launch_bounds__(256) void mark_kernel(
    const int* __restrict__ x, int* __restrict__ slot,
    int* __restrict__ counter, unsigned int* __restrict__ wt) {
  const int i = blockIdx.x * 256 + threadIdx.x;  // B*T = 32768
  if (blockIdx.x < 9) wt[blockIdx.x * 256 + threadIdx.x] = 0;
  const int v = x[i];
  if (atomicCAS(&slot[v], -1, -2147483647) == -1) {
    slot[v] = 1 + atomicAdd(counter, 1);
  }
}

// Transpose W[c][m] -> Wt[s][k][c] bf16, touched rows only.
// grid = (9000, 2): 32-m tiles x 256-c halves. Block 256 threads.
__global__ __launch_bounds__(256) void transpose_kernel(
    const float4* __restrict__ W4, const int* __restrict__ slot,
    unsigned int* __restrict__ wt) {
  __shared__ float tile[32][257];
  __shared__ int sl[5];
  const int bx = blockIdx.x;
  const int m0 = bx * 32;
  const int v0 = m0 / 9;
  const int k0 = m0 - 9 * v0;
  const int c0 = blockIdx.y * 256;
  const int tid = threadIdx.x;
  if (tid < 5) sl[tid] = (v0 + tid < Vc) ? slot[v0 + tid] : -1;
  // load: 8 float4/thread; each wave-inst = 8 x 128B line-aligned segments
#pragma unroll
  for (int p = 0; p < 8; ++p) {
    const int fl = p * 256 + tid;
    const int cl = fl >> 3;       // 0..255
    const int j = fl & 7;         // float4 within the 32-m span
    const float4 f = W4[(size_t)(c0 + cl) * (Mc / 4) + bx * 8 + j];
    tile[4 * j + 0][cl] = f.x;
    tile[4 * j + 1][cl] = f.y;
    tile[4 * j + 2][cl] = f.z;
    tile[4 * j + 3][cl] = f.w;
  }
  __syncthreads();
  // pack: 16 passes; wave-uniform (m, slot); 256B contiguous per wave-inst
  const int h = tid >> 7;   // 0..1
  const int u = tid & 127;  // uint index within 256-c half
#pragma unroll
  for (int p = 0; p < 16; ++p) {
    const int m = 2 * p + h;  // 0..31, wave-uniform
    const int kk = k0 + m;
    const int vl = kk / 9;    // 0..4
    const int k = kk - 9 * vl;
    const int s = sl[vl];
    if (s >= 0) {
      const unsigned int val =
          f2bf(tile[m][2 * u]) | (f2bf(tile[m][2 * u + 1]) << 16);
      wt[(size_t)s * ROW_U + k * 256 + (c0 >> 1) + u] = val;
    }
  }
}

// Gather: grid = 1024 (8 b x 128 t-tiles), block 256 (4 ch/thread).
__global__ __launch_bounds__(256) void gather_kernel(
    const int* __restrict__ x, const int* __restrict__ slot,
    const uint2* __restrict__ wt2, const float* __restrict__ bias,
    float* __restrict__ out) {
  __shared__ int ids[T_TILE + Kc - 1];  // 40 compact slot ids
  const int gb = blockIdx.x;
  const int b = gb >> 7;
  const int t0 = (gb & 127) * T_TILE;
  const int tid = threadIdx.x;
  if (tid < T_TILE + Kc - 1) {
    const int s = t0 + tid - (Kc / 2);
    ids[tid] = (s >= 0 && s < Tc) ? slot[x[b * Tc + s]] : 0;
  }
  __syncthreads();
  const int q = tid & 127;  // c-quad: channels 4q..4q+3
  const int h = tid >> 7;   // t-half
  const f4v b4 = *(const f4v*)(bias + 4 * q);
#pragma unroll
  for (int i = 0; i < 16; ++i) {
    const int tt = h * 16 + i;
    f4v acc = b4;
#pragma unroll
    for (int k = 0; k < Kc; ++k) {
      const int id = ids[tt + k];
      const uint2 wv = wt2[(size_t)id * (ROW_U / 2) + k * 128 + q];
      acc.x += __uint_as_float(wv.x << 16);
      acc.y += __uint_as_float(wv.x & 0xFFFF0000u);
      acc.z += __uint_as_float(wv.y << 16);
      acc.w += __uint_as_float(wv.y & 0xFFFF0000u);
    }
    __builtin_nontemporal_store(
        acc, (f4v*)(out + ((size_t)(b * Tc + t0 + tt) << 9) + 4 * q));
  }
}

// Fallback (ws too small): direct, slow but correct.
__global__ __launch_bounds__(256) void conv_fallback_kernel(
    const int* __restrict__ x, const float* __restrict__ W,
    const float* __restrict__ bias, float* __restrict__ out) {
  const size_t idx = (size_t)blockIdx.x * 256 + threadIdx.x;
  const int c = (int)(idx & (Hc - 1));
  const size_t bt = idx >> 9;
  const int t = (int)(bt & (Tc - 1));
  const int b = (int)(bt >> 12);
  float acc = bias[c];
#pragma unroll
  for (int k = 0; k < Kc; ++k) {
    const int s = t + k - (Kc / 2);
    if (s >= 0 && s < Tc) {
      const int id = x[b * Tc + s];
      acc += W[(size_t)c * Mc + (size_t)id * Kc + k];
    }
  }
  out[idx] = acc;
}

extern "C" void kernel_launch(void* const* d_in, const int* in_sizes, int n_in,
                              void* d_out, int out_size, void* d_ws, size_t ws_size,
                              hipStream_t stream) {
  const int* x = (const int*)d_in[0];
  const float* W = (const float*)d_in[1];
  const float* bias = (const float*)d_in[2];
  float* out = (float*)d_out;

  // ws layout: Wt (WT_ROWS x 9216 B), slot[V], counter
  const size_t wt_bytes = (size_t)WT_ROWS * ROW_U * 4;  // 294,921,216 B
  const size_t slot_off = wt_bytes;
  const size_t cnt_off = slot_off + (size_t)Vc * 4;
  const size_t need = cnt_off + 4;

  if (ws_size >= need) {
    unsigned int* wt = (unsigned int*)d_ws;
    int* slot = (int*)((char*)d_ws + slot_off);
    int* counter = (int*)((char*)d_ws + cnt_off);
    hipMemsetAsync(slot, 0xFF, (size_t)Vc * 4, stream);
    hipMemsetAsync(counter, 0, 4, stream);
    mark_kernel<<<(Bc * Tc) / 256, 256, 0, stream>>>(x, slot, counter, wt);
    dim3 tg(Mc / 32, 2);  // 9000 x 2
    transpose_kernel<<<tg, 256, 0, stream>>>((const float4*)W, slot, wt);
    gather_kernel<<<Bc * (Tc / T_TILE), 256, 0, stream>>>(
        x, slot, (const uint2*)wt, bias, out);
  } else {
    const size_t n = (size_t)Bc * Tc * Hc;
    conv_fallback_kernel<<<(int)(n / 256), 256, 0, stream>>>(x, W, bias, out);
  }
}